// Round 1
// baseline (48.643 us; speedup 1.0000x reference)
//
#include <hip/hip_runtime.h>
#include <hip/hip_bf16.h>
#include <math.h>

typedef short short8 __attribute__((ext_vector_type(8)));
typedef float f32x4 __attribute__((ext_vector_type(4)));

#define NQ 32
#define NDOCS 8
#define QLEN 32
#define DLEN 200
#define DIM 128
#define MD 256          // total docs = NQ*NDOCS
#define DT_TILES 13     // ceil(200/16)
#define ROWB 256        // LDS row stride in bytes (128 bf16)

__device__ __forceinline__ short f2bf(float x) {
    union { float f; unsigned u; } v; v.f = x;
    unsigned r = v.u + 0x7FFFu + ((v.u >> 16) & 1u);  // round-to-nearest-even
    return (short)(r >> 16);
}

// Kernel 0: hq fp32 -> bf16 (131072 elems), 16384 threads x 8 elems
__global__ __launch_bounds__(256) void convert_hq(const float* __restrict__ hq,
                                                  short* __restrict__ hqb) {
    int idx = blockIdx.x * 256 + threadIdx.x;
    const float4* p = reinterpret_cast<const float4*>(hq) + (size_t)idx * 2;
    float4 f0 = p[0], f1 = p[1];
    short8 o;
    o[0] = f2bf(f0.x); o[1] = f2bf(f0.y); o[2] = f2bf(f0.z); o[3] = f2bf(f0.w);
    o[4] = f2bf(f1.x); o[5] = f2bf(f1.y); o[6] = f2bf(f1.z); o[7] = f2bf(f1.w);
    reinterpret_cast<short8*>(hqb)[idx] = o;
}

// Kernel 1: one block per doc m. Stage hd[m] -> LDS bf16 (XOR-swizzled),
// each of 4 waves computes 8 questions: S = hq[n] @ hd[m]^T (32x200),
// running max over d, mean over q -> out[n*MD + m].
__global__ __launch_bounds__(256) void colbert_scores(const float* __restrict__ hd,
                                                      const short* __restrict__ hqb,
                                                      float* __restrict__ out) {
    __shared__ char lds[208 * ROWB];  // 53248 B (rows 200..207 read-only garbage, masked)
    const int m = blockIdx.x;
    const int tid = threadIdx.x;

    // ---- stage hd[m] fp32 -> bf16 LDS, swizzled: byte_in_row ^= (row&7)<<4 ----
    const float* src = hd + (size_t)m * (DLEN * DIM);
    for (int c = tid; c < DLEN * 16; c += 256) {   // 16 chunks of 8 bf16 per row
        int row = c >> 4, kc = c & 15;
        const float4* p = reinterpret_cast<const float4*>(src + row * DIM + kc * 8);
        float4 f0 = p[0], f1 = p[1];
        short8 o;
        o[0] = f2bf(f0.x); o[1] = f2bf(f0.y); o[2] = f2bf(f0.z); o[3] = f2bf(f0.w);
        o[4] = f2bf(f1.x); o[5] = f2bf(f1.y); o[6] = f2bf(f1.z); o[7] = f2bf(f1.w);
        int byte = row * ROWB + ((kc * 16) ^ ((row & 7) << 4));
        *reinterpret_cast<short8*>(&lds[byte]) = o;
    }
    __syncthreads();

    const int wid = tid >> 6;
    const int lane = tid & 63;
    const int lg = lane >> 4;   // 0..3  (k-group)
    const int lr = lane & 15;   // 0..15 (row/col within tile)

    for (int ni = 0; ni < 8; ++ni) {
        const int n = wid * 8 + ni;

        // A fragments: hq[n], 2 q-tiles x 4 k-steps, held in regs across all d-tiles
        short8 a[2][4];
        #pragma unroll
        for (int qt = 0; qt < 2; ++qt)
            #pragma unroll
            for (int s = 0; s < 4; ++s)
                a[qt][s] = *reinterpret_cast<const short8*>(
                    hqb + ((size_t)(n * QLEN + qt * 16 + lr) * DIM + s * 32 + lg * 8));

        f32x4 qmax0, qmax1;
        #pragma unroll
        for (int r4 = 0; r4 < 4; ++r4) { qmax0[r4] = -INFINITY; qmax1[r4] = -INFINITY; }

        #pragma unroll 1
        for (int dt = 0; dt < DT_TILES; ++dt) {
            f32x4 acc0 = {0.f, 0.f, 0.f, 0.f}, acc1 = {0.f, 0.f, 0.f, 0.f};
            const int r = dt * 16 + lr;
            const int rowbase = r * ROWB;
            const int swz = (r & 7) << 4;
            #pragma unroll
            for (int s = 0; s < 4; ++s) {
                int byte = rowbase + ((s * 64 + lg * 16) ^ swz);
                short8 b = *reinterpret_cast<const short8*>(&lds[byte]);
                acc0 = __builtin_amdgcn_mfma_f32_16x16x32_bf16(a[0][s], b, acc0, 0, 0, 0);
                acc1 = __builtin_amdgcn_mfma_f32_16x16x32_bf16(a[1][s], b, acc1, 0, 0, 0);
            }
            // lane holds C[q = qt*16 + lg*4 + r4][d = dt*16 + lr]; mask padded d >= 200
            bool valid = (dt < 12) | (lr < 8);
            #pragma unroll
            for (int r4 = 0; r4 < 4; ++r4) {
                qmax0[r4] = fmaxf(qmax0[r4], valid ? acc0[r4] : -INFINITY);
                qmax1[r4] = fmaxf(qmax1[r4], valid ? acc1[r4] : -INFINITY);
            }
        }

        // max over d: reduce across the 16 lanes (low 4 lane bits) holding different d
        #pragma unroll
        for (int off = 1; off <= 8; off <<= 1) {
            #pragma unroll
            for (int r4 = 0; r4 < 4; ++r4) {
                qmax0[r4] = fmaxf(qmax0[r4], __shfl_xor(qmax0[r4], off, 64));
                qmax1[r4] = fmaxf(qmax1[r4], __shfl_xor(qmax1[r4], off, 64));
            }
        }
        // mean over q: lane (lg) holds q = {lg*4+r4} and {16+lg*4+r4}; sum across lg
        float ssum = qmax0[0] + qmax0[1] + qmax0[2] + qmax0[3]
                   + qmax1[0] + qmax1[1] + qmax1[2] + qmax1[3];
        ssum += __shfl_xor(ssum, 16, 64);
        ssum += __shfl_xor(ssum, 32, 64);
        if (lane == 0) out[n * MD + m] = ssum * (1.0f / 32.0f);
    }
}

// Kernel 2: loss = mean_n( logsumexp(row_n) - row_n[8n] ), rows of 256
__global__ __launch_bounds__(256) void colbert_loss(const float* __restrict__ scores,
                                                    float* __restrict__ loss_out) {
    __shared__ float terms[NQ];
    const int tid = threadIdx.x;
    const int wid = tid >> 6, lane = tid & 63;
    for (int n = wid; n < NQ; n += 4) {
        const float* row = scores + n * MD;
        float v0 = row[lane], v1 = row[64 + lane], v2 = row[128 + lane], v3 = row[192 + lane];
        float mx = fmaxf(fmaxf(v0, v1), fmaxf(v2, v3));
        #pragma unroll
        for (int off = 1; off < 64; off <<= 1) mx = fmaxf(mx, __shfl_xor(mx, off, 64));
        float s = expf(v0 - mx) + expf(v1 - mx) + expf(v2 - mx) + expf(v3 - mx);
        #pragma unroll
        for (int off = 1; off < 64; off <<= 1) s += __shfl_xor(s, off, 64);
        if (lane == 0) terms[n] = (mx + logf(s)) - row[n * NDOCS];
    }
    __syncthreads();
    if (tid == 0) {
        float acc = 0.f;
        #pragma unroll
        for (int n = 0; n < NQ; ++n) acc += terms[n];
        loss_out[0] = acc * (1.0f / NQ);
    }
}

extern "C" void kernel_launch(void* const* d_in, const int* in_sizes, int n_in,
                              void* d_out, int out_size, void* d_ws, size_t ws_size,
                              hipStream_t stream) {
    const float* hq = (const float*)d_in[0];   // [32][32][128] f32
    const float* hd = (const float*)d_in[1];   // [256][200][128] f32
    float* out = (float*)d_out;                // 8192 scores + 1 loss
    short* hqb = (short*)d_ws;                 // 131072 bf16 = 256 KB scratch

    convert_hq<<<64, 256, 0, stream>>>(hq, hqb);
    colbert_scores<<<MD, 256, 0, stream>>>(hd, hqb, out);
    colbert_loss<<<1, 256, 0, stream>>>(out, out + NQ * MD);
}